// Round 8
// baseline (120.770 us; speedup 1.0000x reference)
//
#include <hip/hip_runtime.h>
#include <hip/hip_bf16.h>

namespace {

constexpr int Bn = 2, Sn = 2048, Hn = 16, Dn = 128;
constexpr int QBLK = 128;   // 2 groups x 4 waves x 32 queries
constexpr int KVBLK = 32;   // keys per chunk; superstep = 2 chunks (even/odd group)
constexpr int RS = Hn * Dn; // 2048 floats
constexpr float QSCALE = 0.08838834764831845f * 1.4426950408889634f; // 1/sqrt(D)*log2(e)

// bf16 K/V images, pre-swizzled to the exact LDS chunk layout.
// 2048 chunks (2*16*64) x 8192 B each, K then V.
constexpr size_t IMG_BYTES = (size_t)Bn * Hn * 64 * 8192;   // 16 MB
constexpr size_t WS_NEED   = 2 * IMG_BYTES;                 // 32 MB

typedef __bf16 bf16x8 __attribute__((ext_vector_type(8)));
typedef __bf16 bf16x4 __attribute__((ext_vector_type(4)));
typedef float  f32x16 __attribute__((ext_vector_type(16)));

__device__ __forceinline__ f32x16 mfma32(bf16x8 a, bf16x8 b, f32x16 c) {
  return __builtin_amdgcn_mfma_f32_32x32x16_bf16(a, b, c, 0, 0, 0);
}
__device__ __forceinline__ unsigned pack2(float a, float b) {
  union { __bf16 h[2]; unsigned u; } r;
  r.h[0] = (__bf16)a; r.h[1] = (__bf16)b;
  return r.u;
}
// lane<->lane^32 exchange on the VALU pipe (T12 primitive).
__device__ __forceinline__ float pair_max(float x, int hi) {
  auto r = __builtin_amdgcn_permlane32_swap(__float_as_uint(x), __float_as_uint(x), false, false);
  const float sw = __uint_as_float(hi ? r[0] : r[1]);
  return fmaxf(x, sw);
}
__device__ __forceinline__ float pair_sum(float x, int hi) {
  auto r = __builtin_amdgcn_permlane32_swap(__float_as_uint(x), __float_as_uint(x), false, false);
  const float sw = __uint_as_float(hi ? r[0] : r[1]);
  return x + sw;
}
__device__ __forceinline__ float f4e(const float4& v, int j) {
  return j == 0 ? v.x : j == 1 ? v.y : j == 2 ? v.z : v.w;
}
__device__ __forceinline__ float lane_bcast(int row, float v) {
  return __uint_as_float(__builtin_amdgcn_ds_bpermute(row * 4, __float_as_uint(v)));
}

// async 16B global->LDS DMA (linear dest: uniform lds base + lane*16)
__device__ __forceinline__ void cp16(const char* g, char* l) {
  __builtin_amdgcn_global_load_lds(
      (const __attribute__((address_space(1))) void*)g,
      (__attribute__((address_space(3))) void*)l, 16, 0, 0);
}

// full barrier: DMA'd LDS + ds ops visible to all waves.
__device__ __forceinline__ void dma_barrier() {
  __builtin_amdgcn_sched_barrier(0);
  asm volatile("s_waitcnt vmcnt(0) lgkmcnt(0)" ::: "memory");
  __builtin_amdgcn_s_barrier();
  __builtin_amdgcn_sched_barrier(0);
}
// lgkm-only barrier (fallback kernel): leaves reg-destined prefetches in flight.
__device__ __forceinline__ void pipeline_barrier() {
  __builtin_amdgcn_sched_barrier(0);
  asm volatile("s_waitcnt lgkmcnt(0)" ::: "memory");
  __builtin_amdgcn_s_barrier();
  __builtin_amdgcn_sched_barrier(0);
}

// ============================================================================
// Pre-pass: fp32 K/V -> bf16 images in the EXACT swizzled LDS chunk layout.
// (verbatim from R6, verified)
// ============================================================================
__global__ __launch_bounds__(256)
void prep_kv(const float* __restrict__ K, const float* __restrict__ V,
             __bf16* __restrict__ KI, __bf16* __restrict__ VI)
{
  const int gid  = (int)blockIdx.x * 256 + (int)threadIdx.x; // 0..2M
  const int half = gid >> 20;              // 0=K, 1=V
  const int id   = gid & ((1 << 20) - 1);  // 0..1M
  const int chunk = id >> 9;               // 0..2047
  const int rem   = id & 511;
  const int bh = chunk >> 6, c = chunk & 63;
  const int b = bh >> 4, h = bh & 15;
  if (half == 0) {
    const int key = rem >> 4, dblk = rem & 15;
    const float* src = K + ((size_t)b * Sn + (size_t)c * 32 + key) * RS + h * Dn + dblk * 8;
    float4 a  = *(const float4*)src;
    float4 c2 = *(const float4*)(src + 4);
    bf16x8 f;
    f[0] = (__bf16)a.x;  f[1] = (__bf16)a.y;  f[2] = (__bf16)a.z;  f[3] = (__bf16)a.w;
    f[4] = (__bf16)c2.x; f[5] = (__bf16)c2.y; f[6] = (__bf16)c2.z; f[7] = (__bf16)c2.w;
    char* dst = (char*)KI + (size_t)chunk * 8192 + ((key * 256 + dblk * 16) ^ ((key & 7) << 4));
    *(bf16x8*)dst = f;
  } else {
    const int d = rem >> 2, koct = rem & 3;
    const float* src = V + ((size_t)b * Sn + (size_t)c * 32 + koct * 8) * RS + h * Dn + d;
    bf16x8 f;
#pragma unroll
    for (int j = 0; j < 8; ++j) f[j] = (__bf16)src[(size_t)j * RS];
    const int off = (d * 64 + koct * 16) ^ ((d & 3) << 4) ^ (((d >> 3) & 1) << 6);
    *(bf16x8*)((char*)VI + (size_t)chunk * 8192 + off) = f;
  }
}

// ============================================================================
// Main kernel: 512 blocks x 512 threads, 64 KB LDS -> 2 blocks/CU.
// R8 mapping: co-resident pair (bid, bid+256) = SAME qt, DIFFERENT head
// (qt = s&15, hidx = xcd*4 + (s>>4)). Both partners have identical
// T = 2(qt+1) and fully-overlapped lifetimes -> every active CU runs 16
// waves (4/SIMD) for its whole duration (R6/R7 effectively ran 2/SIMD).
// Staging = 4 global_load_lds per wave per superstep from the pre-swizzled
// images. K ring-4, V ring-4. Inner compute = verified R6.
// ============================================================================
__global__ __launch_bounds__(512)
void fa_fwd_dma(const float* __restrict__ Q, const __bf16* __restrict__ KI,
                const __bf16* __restrict__ VI, float* __restrict__ O)
{
  __shared__ __align__(16) __bf16 Klds[4][4096]; // 32 KB, ring by chunk &3
  __shared__ __align__(16) __bf16 Vt[4][4096];   // 32 KB, ring by chunk &3

  const int tid  = threadIdx.x;
  const int lane = tid & 63;
  const int wave = tid >> 6;
  const int col  = lane & 31;
  const int hi   = lane >> 5;
  const int grp  = wave >> 2;   // 0: even chunks, 1: odd chunks
  const int wq   = wave & 3;

  // R8: same-qt pairing across heads. bid = xcd + 8*(qt + 16*h2).
  const int xcd  = (int)blockIdx.x & 7;
  const int s    = (int)blockIdx.x >> 3;    // 0..63
  const int qt   = s & 15;                  // 0..15 (pair bid,bid+256: same qt)
  const int hidx = xcd * 4 + (s >> 4);      // 0..31
  const int b    = hidx >> 4, h = hidx & 15;
  const int q0w  = qt * QBLK + wq * 32;
  const int T    = 2 * (qt + 1);            // supersteps
  const size_t base = ((size_t)b * Sn) * RS + (size_t)h * Dn;

  const char* KIc = (const char*)KI + (size_t)hidx * 64 * 8192;
  const char* VIc = (const char*)VI + (size_t)hidx * 64 * 8192;

  // staging roles: waves 0-3 stage K (2 chunks), 4-7 stage V (2 chunks).
  const int sr = wave >> 1;           // 0..3
  const int hb = (wave & 1) * 4096;   // byte half of an 8 KB chunk
  auto stageK2 = [&](int ss) {        // chunks 2ss, 2ss+1
    if (sr < 2) {
      const int ck = 2 * ss + sr;
      const char* g = KIc + (size_t)ck * 8192 + hb;
      char* l = (char*)&Klds[ck & 3][0] + hb;
#pragma unroll
      for (int i = 0; i < 4; ++i) cp16(g + i * 1024 + lane * 16, l + i * 1024);
    }
  };
  auto stageV2 = [&](int ss) {
    if (sr >= 2) {
      const int cv = 2 * ss + (sr - 2);
      const char* g = VIc + (size_t)cv * 8192 + hb;
      char* l = (char*)&Vt[cv & 3][0] + hb;
#pragma unroll
      for (int i = 0; i < 4; ++i) cp16(g + i * 1024 + lane * 16, l + i * 1024);
    }
  };

  const int cswz = (col & 7) << 4;
  const int vswz = ((col & 3) << 4) ^ (((col >> 3) & 1) << 6);

  // ---- Q fragments, scaled ----
  bf16x8 qf[8];
  {
    const float* qp = Q + base + (size_t)(q0w + col) * RS + hi * 8;
#pragma unroll
    for (int kk = 0; kk < 8; ++kk) {
      float4 a = *(const float4*)(qp + kk * 16);
      float4 c2 = *(const float4*)(qp + kk * 16 + 4);
      bf16x8 f;
      f[0] = (__bf16)(a.x * QSCALE);  f[1] = (__bf16)(a.y * QSCALE);
      f[2] = (__bf16)(a.z * QSCALE);  f[3] = (__bf16)(a.w * QSCALE);
      f[4] = (__bf16)(c2.x * QSCALE); f[5] = (__bf16)(c2.y * QSCALE);
      f[6] = (__bf16)(c2.z * QSCALE); f[7] = (__bf16)(c2.w * QSCALE);
      qf[kk] = f;
    }
  }

  f32x16 o0 = {}, o1 = {}, o2 = {}, o3 = {};
  float m = -1e30f, l = 0.f;

  // ---- prologue: DMA K(0),V(0),K(1); wait; S(0); fence ----
  stageK2(0);
  stageV2(0);
  stageK2(1);
  dma_barrier();                // K0,K1,V0 in LDS (vmcnt(0) covers Q loads too)

  f32x16 st_cur = {};
  if (grp * KVBLK <= q0w + 31) {
    const char* kb = (const char*)&Klds[grp][0];
    __builtin_amdgcn_s_setprio(1);
#pragma unroll
    for (int kk = 0; kk < 8; ++kk) {
      bf16x8 ka = *(const bf16x8*)(kb + ((col * 256 + kk * 32 + hi * 16) ^ cswz));
      st_cur = mfma32(ka, qf[kk], st_cur);
    }
    __builtin_amdgcn_s_setprio(0);
  }
  dma_barrier();                // fence S(0) slot-0/1 reads vs iter-0 K(2) DMA

#pragma unroll 1
  for (int t = 0; t < T; ++t) {
    // ---- issue next DMAs first: K(t+2) -> slots (2t)&3,(2t+1)&3 (reads
    // drained at iter t-1 barrier); V(t+1) -> slots (2t+2)&3,(2t+3)&3 ----
    if (t + 2 < T) stageK2(t + 2);
    if (t + 1 < T) stageV2(t + 1);

    // ---- QK^T(t+1) on the MFMA pipe ----
    f32x16 stn = {};
    const int icn = 2 * (t + 1) + grp;
    if (t + 1 < T && icn * KVBLK <= q0w + 31) {
      const char* kb = (const char*)&Klds[icn & 3][0];
      __builtin_amdgcn_s_setprio(1);
#pragma unroll
      for (int kk = 0; kk < 8; ++kk) {
        bf16x8 ka = *(const bf16x8*)(kb + ((col * 256 + kk * 32 + hi * 16) ^ cswz));
        stn = mfma32(ka, qf[kk], stn);
      }
      __builtin_amdgcn_s_setprio(0);
    }

    // ---- finish chunk t: mask, softmax, repack, PV ----
    const int kv0 = (2 * t + grp) * KVBLK;
    if (kv0 <= q0w + 31) {
      if (kv0 + KVBLK - 1 > q0w) {
        const int qk = q0w + col - kv0;
#pragma unroll
        for (int r = 0; r < 16; ++r) {
          const int krow = (r & 3) + 8 * (r >> 2) + 4 * hi;
          st_cur[r] = (krow <= qk) ? st_cur[r] : -1e30f;
        }
      }

      float t8[8];
#pragma unroll
      for (int r = 0; r < 8; ++r) t8[r] = fmaxf(st_cur[r], st_cur[r + 8]);
#pragma unroll
      for (int r = 0; r < 4; ++r) t8[r] = fmaxf(t8[r], t8[r + 4]);
      const float pmax = pair_max(fmaxf(fmaxf(t8[0], t8[1]), fmaxf(t8[2], t8[3])), hi);

      if (!__all(pmax <= m + 11.0f)) {   // T13 defer-max
        const float mnew = fmaxf(m, pmax);
        const float al = __builtin_amdgcn_exp2f(m - mnew);
        m = mnew;
        l *= al;
#pragma unroll
        for (int r = 0; r < 16; ++r) {
          const int row = (r & 3) + 8 * (r >> 2) + 4 * hi;
          const float ar = lane_bcast(row, al);
          o0[r] *= ar; o1[r] *= ar; o2[r] *= ar; o3[r] *= ar;
        }
      }

      float s4[4] = {0.f, 0.f, 0.f, 0.f};
#pragma unroll
      for (int r = 0; r < 16; ++r) {
        st_cur[r] = __builtin_amdgcn_exp2f(st_cur[r] - m);
        s4[r & 3] += st_cur[r];
      }
      l += pair_sum((s4[0] + s4[1]) + (s4[2] + s4[3]), hi);

      // P -> A-fragments via 4 permlane32_swap
      unsigned cw[8];
#pragma unroll
      for (int i = 0; i < 8; ++i) cw[i] = pack2(st_cur[2 * i], st_cur[2 * i + 1]);
      union { unsigned u[4]; bf16x8 v; } pa0, pa1;
      {
        auto s02 = __builtin_amdgcn_permlane32_swap(cw[0], cw[2], false, false);
        auto s13 = __builtin_amdgcn_permlane32_swap(cw[1], cw[3], false, false);
        auto s46 = __builtin_amdgcn_permlane32_swap(cw[4], cw[6], false, false);
        auto s57 = __builtin_amdgcn_permlane32_swap(cw[5], cw[7], false, false);
        pa0.u[0] = s02[0]; pa0.u[2] = s02[1];
        pa0.u[1] = s13[0]; pa0.u[3] = s13[1];
        pa1.u[0] = s46[0]; pa1.u[2] = s46[1];
        pa1.u[1] = s57[0]; pa1.u[3] = s57[1];
      }

      const char* vb = (const char*)&Vt[(2 * t + grp) & 3][0];
      __builtin_amdgcn_s_setprio(1);
#pragma unroll
      for (int ks = 0; ks < 2; ++ks) {
        const bf16x8 pa = ks ? pa1.v : pa0.v;
#define PV_STEP(ovar, dt) { \
        bf16x8 vf = *(const bf16x8*)(vb + ((((dt)*32 + col) * 64 + ks * 32 + hi * 16) ^ vswz)); \
        ovar = mfma32(pa, vf, ovar); }
        PV_STEP(o0, 0) PV_STEP(o1, 1) PV_STEP(o2, 2) PV_STEP(o3, 3)
#undef PV_STEP
      }
      __builtin_amdgcn_s_setprio(0);
    }
    dma_barrier();
    st_cur = stn;
  }

  // ---- merge group-1 partials into group-0 (LDS scratch over K/V rings) ----
  float* ob  = reinterpret_cast<float*>(&Klds[0][0]);   // 8192 floats (32 KB)
  float* mlb = reinterpret_cast<float*>(&Vt[0][0]);
  if (grp == 1) {
    mlb[wq * 128 + lane] = m;
    mlb[wq * 128 + 64 + lane] = l;
#pragma unroll
    for (int r = 0; r < 16; ++r) {
      ob[wq * 1024 + r * 64 + lane] = o0[r];
      ob[4096 + wq * 1024 + r * 64 + lane] = o1[r];
    }
  }
  __syncthreads();
  float f0 = 1.f, f1 = 0.f;
  if (grp == 0) {
    const float m1 = mlb[wq * 128 + lane];
    const float l1 = mlb[wq * 128 + 64 + lane];
    const float mS = fmaxf(m, m1);
    f0 = __builtin_amdgcn_exp2f(m - mS);
    f1 = __builtin_amdgcn_exp2f(m1 - mS);
    l = l * f0 + l1 * f1;
#pragma unroll
    for (int r = 0; r < 16; ++r) {
      const int row = (r & 3) + 8 * (r >> 2) + 4 * hi;
      const float a0 = lane_bcast(row, f0), a1 = lane_bcast(row, f1);
      o0[r] = o0[r] * a0 + ob[wq * 1024 + r * 64 + lane] * a1;
      o1[r] = o1[r] * a0 + ob[4096 + wq * 1024 + r * 64 + lane] * a1;
    }
  }
  __syncthreads();
  if (grp == 1) {
#pragma unroll
    for (int r = 0; r < 16; ++r) {
      ob[wq * 1024 + r * 64 + lane] = o2[r];
      ob[4096 + wq * 1024 + r * 64 + lane] = o3[r];
    }
  }
  __syncthreads();
  if (grp == 0) {
#pragma unroll
    for (int r = 0; r < 16; ++r) {
      const int row = (r & 3) + 8 * (r >> 2) + 4 * hi;
      const float a0 = lane_bcast(row, f0), a1 = lane_bcast(row, f1);
      o2[r] = o2[r] * a0 + ob[wq * 1024 + r * 64 + lane] * a1;
      o3[r] = o3[r] * a0 + ob[4096 + wq * 1024 + r * 64 + lane] * a1;
    }
    const float linv = 1.0f / l;
#pragma unroll
    for (int r = 0; r < 16; ++r) {
      const int row = (r & 3) + 8 * (r >> 2) + 4 * hi;
      const float lr = lane_bcast(row, linv);
      float* op = O + base + (size_t)(q0w + row) * RS + col;
      op[0]  = o0[r] * lr;
      op[32] = o1[r] * lr;
      op[64] = o2[r] * lr;
      op[96] = o3[r] * lr;
    }
  }
}

// ============================================================================
// Fallback: verbatim R5 kernel (104 µs) if workspace is too small.
// ============================================================================
__global__ __launch_bounds__(512)
void fa_fwd_reg(const float* __restrict__ Q, const float* __restrict__ K,
                const float* __restrict__ V, float* __restrict__ O)
{
  __shared__ __align__(16) __bf16 Klds[6][KVBLK * 128];
  __shared__ __align__(16) __bf16 Vt[4][128 * KVBLK];

  const int tid  = threadIdx.x;
  const int lane = tid & 63;
  const int wave = tid >> 6;
  const int col  = lane & 31;
  const int hi   = lane >> 5;
  const int grp  = wave >> 2;
  const int wq   = wave & 3;

  const int xcd  = (int)blockIdx.x & 7;
  const int s    = (int)blockIdx.x >> 3;
  const int hidx = xcd * 4 + (s & 3);
  const int b    = hidx >> 4, h = hidx & 15;
  const int s2   = s >> 2;
  const int qt   = (s < 32) ? (15 - s2) : (s2 - 8);
  const int q0w  = qt * QBLK + wq * 32;
  const int T    = 2 * (qt + 1);
  const size_t base = ((size_t)b * Sn) * RS + (size_t)h * Dn;

  const int sthalf = tid >> 8, ht = tid & 255;
  const int skey = ht >> 3, sd = (ht & 7) * 16;
  const int vkey4 = (ht & 7) * 4, vd4 = (ht >> 3) * 4;

  float4 kr[4], vr[4];
  auto loadK = [&](int ss) {
    const int kv0 = (2 * ss + sthalf) * KVBLK;
    const float* kp = K + base + (size_t)(kv0 + skey) * RS + sd;
#pragma unroll
    for (int i = 0; i < 4; ++i) kr[i] = *(const float4*)(kp + 4 * i);
  };
  auto loadV = [&](int ss) {
    const int kv0 = (2 * ss + sthalf) * KVBLK;
    const float* vp = V + base + (size_t)(kv0 + vkey4) * RS + vd4;
#pragma unroll
    for (int i = 0; i < 4; ++i) vr[i] = *(const float4*)(vp + (size_t)i * RS);
  };
  auto stageK = [&](int ss) {
    char* kb = (char*)&Klds[(2 * ss + sthalf) % 6][0];
    const int kbase = skey * 256 + sd * 2;
    const int kswz  = (skey & 7) << 4;
#pragma unroll
    for (int i = 0; i < 2; ++i) {
      bf16x8 f;
      f[0] = (__bf16)kr[2*i].x;   f[1] = (__bf16)kr[2*i].y;
      f[2] = (__bf16)kr[2*i].z;   f[3] = (__bf16)kr[2*i].w;
      f[4] = (__bf16)kr[2*i+1].x; f[5] = (__bf16)kr[2*i+1].y;
      f[6] = (__bf16)kr[2*i+1].z; f[7] = (__bf16)kr[2*i+1].w;
      *(bf16x8*)(kb + ((kbase + 16 * i) ^ kswz)) = f;
    }
  };
  auto stageV = [&](int ss) {
    char* vb = (char*)&Vt[(2 * ss + sthalf) & 3][0];
    const int b6 = ((vd4 >> 3) & 1) << 6;
#pragma unroll
    for (int j = 0; j < 4; ++j) {
      bf16x4 w;
      w[0] = (__bf16)f4e(vr[0], j);
      w[1] = (__bf16)f4e(vr[1], j);
      w[2] = (__bf16)f4e(vr[2], j);
      w[3] = (__bf16)f4e(vr[3], j);
      const int addr = (((vd4 + j) * 64 + vkey4 * 2) ^ (j << 4)) ^ b6;
      *(bf16x4*)(vb + addr) = w;
    }
  };

  const int cswz = (col & 7) << 4;
  const int vswz = ((col & 3) << 4) ^ (((col >> 3) & 1) << 6);

  bf16x8 qf[8];
  {
    const float* qp = Q + base + (size_t)(q0w + col) * RS + hi * 8;
#pragma unroll
    for (int kk = 0; kk < 8; ++kk) {
      float4 a = *(const float4*)(qp + kk * 16);
      float4 c2 = *(const float4*)(qp + kk * 16 + 4);
      bf16x8 f;
      f[0] = (__bf16)(a.x * QSCALE);  f[1] = (__bf16)(a.y * QSCALE);
      f[2] = (__bf16)(a.z * QSCALE);  f[3] = (__bf16)(a.w * QSCALE);
      f[4] = (__bf16)(c2.x * QSCALE); f[5] = (__bf16)(c2.y * QSCALE);
      f[6] = (__bf16)(c2.z * QSCALE); f[7] = (__bf16)(c2.w * QSCALE);
      qf[kk] = f;
    }
  }

  f32x16 o0 = {}, o1 = {}, o2 = {}, o3 = {};
  float m = -1e30f, l = 0.f;

  loadK(0); loadV(0);
  stageK(0);
  loadK(1);
  stageV(0);
  loadV(1);
  stageK(1);
  if (2 < T) loadK(2);
  pipeline_barrier();

  f32x16 st_cur = {};
  if (grp * KVBLK <= q0w + 31) {
    const char* kb = (const char*)&Klds[grp][0];
    __builtin_amdgcn_s_setprio(1);
#pragma unroll
    for (int kk = 0; kk < 8; ++kk) {
      bf16x8 ka = *(const bf16x8*)(kb + ((col * 256 + kk * 32 + hi * 16) ^ cswz));
      st_cur = mfma32(ka, qf[kk], st_cur);
    }
    __builtin_amdgcn_s_setprio(0);
  }

#pragma unroll 1
  for (int t = 0; t < T; ++t) {
    f32x16 stn = {};
    const int icn = 2 * (t + 1) + grp;
    if (t + 1 < T && icn * KVBLK <= q0w + 31) {
      const char* kb = (const char*)&Klds[icn % 6][0];
      __builtin_amdgcn_s_setprio(1);
#pragma unroll
      for (int kk = 0; kk < 8; ++kk) {
        bf16x8 ka = *(const bf16x8*)(kb + ((col * 256 + kk * 32 + hi * 16) ^ cswz));
        stn = mfma32(ka, qf[kk], stn);
      }
      __builtin_amdgcn_s_setprio(0);
    }

    if (t + 2 < T) stageK(t + 2);
    if (t + 1 < T) stageV(t + 1);
    if (t + 3 < T) loadK(t + 3);
    if (t + 2 < T) loadV(t + 2);

    const int kv0 = (2 * t + grp) * KVBLK;
    if (kv0 <= q0w + 31) {
      if (kv0 + KVBLK - 1 > q0w) {
        const int qk = q0w + col - kv0;
#pragma unroll
        for (int r = 0; r < 16; ++r) {
          const int krow = (r & 3) + 8 * (r >> 2) + 4 * hi;
          st_cur[r] = (krow <= qk) ? st_cur[r] : -1e30f;
        }
      }

      float t8[8];
#pragma unroll
      for (int r = 0; r < 8; ++r) t8[r] = fmaxf(st_cur[r], st_cur[r + 8]);
#pragma unroll
      for (int r = 0; r < 4; ++r) t8[r] = fmaxf(t8[r], t8[r + 4]);
      const float pmax = pair_max(fmaxf(fmaxf(t8[0], t8[1]), fmaxf(t8[2], t8[3])), hi);

      if (!__all(pmax <= m + 11.0f)) {
        const float mnew = fmaxf(m, pmax);
        const float al = __builtin_amdgcn_exp2f(m - mnew);
        m = mnew;
        l *= al;
#pragma unroll
        for (int r = 0; r < 16; ++r) {
          const int row = (r & 3) + 8 * (r >> 2) + 4 * hi;
          const float ar = lane_bcast(row, al);
          o0[r] *= ar; o1[r] *= ar; o2[r] *= ar; o3[r] *= ar;
        }
      }

      float s4[4] = {0.f, 0.f, 0.f, 0.f};
#pragma unroll
      for (int r = 0; r < 16; ++r) {
        st_cur[r] = __builtin_amdgcn_exp2f(st_cur[r] - m);
        s4[r & 3] += st_cur[r];
      }
      l += pair_sum((s4[0] + s4[1]) + (s4[2] + s4[3]), hi);

      unsigned cw[8];
#pragma unroll
      for (int i = 0; i < 8; ++i) cw[i] = pack2(st_cur[2 * i], st_cur[2 * i + 1]);
      union { unsigned u[4]; bf16x8 v; } pa0, pa1;
      {
        auto s02 = __builtin_amdgcn_permlane32_swap(cw[0], cw[2], false, false);
        auto s13 = __builtin_amdgcn_permlane32_swap(cw[1], cw[3], false, false);
        auto s46 = __builtin_amdgcn_permlane32_swap(cw[4], cw[6], false, false);
        auto s57 = __builtin_amdgcn_permlane32_swap(cw[5], cw[7], false, false);
        pa0.u[0] = s02[0]; pa0.u[2] = s02[1];
        pa0.u[1] = s13[0]; pa0.u[3] = s13[1];
        pa1.u[0] = s46[0]; pa1.u[2] = s46[1];
        pa1.u[1] = s57[0]; pa1.u[3] = s57[1];
      }

      const char* vb = (const char*)&Vt[(2 * t + grp) & 3][0];
      __builtin_amdgcn_s_setprio(1);
#pragma unroll
      for (int ks = 0; ks < 2; ++ks) {
        const bf16x8 pa = ks ? pa1.v : pa0.v;
#define PV_STEP(ovar, dt) { \
        bf16x8 vf = *(const bf16x8*)(vb + ((((dt)*32 + col) * 64 + ks * 32 + hi * 16) ^ vswz)); \
        ovar = mfma32(pa, vf, ovar); }
        PV_STEP(o0, 0) PV_STEP(o1, 1) PV_STEP(o2, 2) PV_STEP(o3, 3)
#undef PV_STEP
      }
      __builtin_amdgcn_s_setprio(0);
    }
    pipeline_barrier();
    st_cur = stn;
  }

  float* ob  = reinterpret_cast<float*>(&Klds[0][0]);
  float* mlb = reinterpret_cast<float*>(&Vt[0][0]);
  if (grp == 1) {
    mlb[wq * 128 + lane] = m;
    mlb[wq * 128 + 64 + lane] = l;
#pragma unroll
    for (int r = 0; r < 16; ++r) {
      ob[wq * 1024 + r * 64 + lane] = o0[r];
      ob[4096 + wq * 1024 + r * 64 + lane] = o1[r];
    }
  }
  __syncthreads();
  float f0 = 1.f, f1 = 0.f;
  if (grp == 0) {
    const float m1 = mlb[wq * 128 + lane];
    const float l1 = mlb[wq * 128 + 64 + lane];
    const float mS = fmaxf(m, m1);
    f0 = __builtin_amdgcn_exp2f(m - mS);
    f1 = __builtin_amdgcn_exp2f(m1 - mS);
    l = l * f0 + l1 * f1;
#pragma unroll
    for (int r = 0; r < 16; ++r) {
      const int row = (r & 3) + 8 * (r >> 2) + 4 * hi;
      const float a0 = lane_bcast(row, f0), a1 = lane_bcast(row, f1);
      o0[r] = o0[r] * a0 + ob[wq * 1024 + r * 64 + lane] * a1;
      o1[r] = o1[r] * a0 + ob[4096 + wq * 1024 + r * 64 + lane] * a1;
    }
  }
  __syncthreads();
  if (grp == 1) {
#pragma unroll
    for (int r = 0; r < 16; ++r) {
      ob[wq * 1024 + r * 64 + lane] = o2[r];
      ob[4096 + wq * 1024 + r * 64 + lane] = o3[r];
    }
  }
  __syncthreads();
  if (grp == 0) {
#pragma unroll
    for (int r = 0; r < 16; ++r) {
      const int row = (r & 3) + 8 * (r >> 2) + 4 * hi;
      const float a0 = lane_bcast(row, f0), a1 = lane_bcast(row, f1);
      o2[r] = o2[r] * a0 + ob[wq * 1024 + r * 64 + lane] * a1;
      o3[r] = o3[r] * a0 + ob[4096 + wq * 1024 + r * 64 + lane] * a1;
    }
    const float linv = 1.0f / l;
#pragma unroll
    for (int r = 0; r < 16; ++r) {
      const int row = (r & 3) + 8 * (r >> 2) + 4 * hi;
      const float lr = lane_bcast(row, linv);
      float* op = O + base + (size_t)(q0w + row) * RS + col;
      op[0]  = o0[r] * lr;
      op[32] = o1[r] * lr;
      op[64] = o2[r] * lr;
      op[96] = o3[r] * lr;
    }
  }
}

} // namespace

extern "C" void kernel_launch(void* const* d_in, const int* /*in_sizes*/, int /*n_in*/,
                              void* d_out, int /*out_size*/, void* d_ws, size_t ws_size,
                              hipStream_t stream) {
  const float* q = (const float*)d_in[0];
  const float* k = (const float*)d_in[1];
  const float* v = (const float*)d_in[2];
  float* o = (float*)d_out;
  if (d_ws != nullptr && ws_size >= WS_NEED) {
    __bf16* ki = (__bf16*)d_ws;
    __bf16* vi = (__bf16*)((char*)d_ws + IMG_BYTES);
    hipLaunchKernelGGL(prep_kv, dim3(8192), dim3(256), 0, stream, k, v, ki, vi);
    hipLaunchKernelGGL(fa_fwd_dma, dim3(512), dim3(512), 0, stream, q, ki, vi, o);
  } else {
    hipLaunchKernelGGL(fa_fwd_reg, dim3(512), dim3(512), 0, stream, q, k, v, o);
  }
}

// Round 9
// 116.073 us; speedup vs baseline: 1.0405x; 1.0405x over previous
//
#include <hip/hip_runtime.h>
#include <hip/hip_bf16.h>

namespace {

constexpr int Bn = 2, Sn = 2048, Hn = 16, Dn = 128;
constexpr int QBLK = 128;   // queries per tile
constexpr int KVBLK = 32;   // image chunk granularity (32 keys / 8 KB)
constexpr int RS = Hn * Dn; // 2048 floats
constexpr float QSCALE = 0.08838834764831845f * 1.4426950408889634f; // 1/sqrt(D)*log2(e)

// bf16 K/V images, pre-swizzled to the exact LDS chunk layout.
constexpr size_t IMG_BYTES = (size_t)Bn * Hn * 64 * 8192;   // 16 MB
constexpr size_t WS_NEED   = 2 * IMG_BYTES;                 // 32 MB

typedef __bf16 bf16x8 __attribute__((ext_vector_type(8)));
typedef __bf16 bf16x4 __attribute__((ext_vector_type(4)));
typedef float  f32x16 __attribute__((ext_vector_type(16)));

__device__ __forceinline__ f32x16 mfma32(bf16x8 a, bf16x8 b, f32x16 c) {
  return __builtin_amdgcn_mfma_f32_32x32x16_bf16(a, b, c, 0, 0, 0);
}
__device__ __forceinline__ unsigned pack2(float a, float b) {
  union { __bf16 h[2]; unsigned u; } r;
  r.h[0] = (__bf16)a; r.h[1] = (__bf16)b;
  return r.u;
}
// lane<->lane^32 exchange on the VALU pipe (T12 primitive).
__device__ __forceinline__ float pair_max(float x, int hi) {
  auto r = __builtin_amdgcn_permlane32_swap(__float_as_uint(x), __float_as_uint(x), false, false);
  const float sw = __uint_as_float(hi ? r[0] : r[1]);
  return fmaxf(x, sw);
}
__device__ __forceinline__ float pair_sum(float x, int hi) {
  auto r = __builtin_amdgcn_permlane32_swap(__float_as_uint(x), __float_as_uint(x), false, false);
  const float sw = __uint_as_float(hi ? r[0] : r[1]);
  return x + sw;
}
__device__ __forceinline__ float f4e(const float4& v, int j) {
  return j == 0 ? v.x : j == 1 ? v.y : j == 2 ? v.z : v.w;
}
__device__ __forceinline__ float lane_bcast(int row, float v) {
  return __uint_as_float(__builtin_amdgcn_ds_bpermute(row * 4, __float_as_uint(v)));
}

// async 16B global->LDS DMA (linear dest: uniform lds base + lane*16)
__device__ __forceinline__ void cp16(const char* g, char* l) {
  __builtin_amdgcn_global_load_lds(
      (const __attribute__((address_space(1))) void*)g,
      (__attribute__((address_space(3))) void*)l, 16, 0, 0);
}

__device__ __forceinline__ void dma_barrier() {
  __builtin_amdgcn_sched_barrier(0);
  asm volatile("s_waitcnt vmcnt(0) lgkmcnt(0)" ::: "memory");
  __builtin_amdgcn_s_barrier();
  __builtin_amdgcn_sched_barrier(0);
}
__device__ __forceinline__ void pipeline_barrier() {
  __builtin_amdgcn_sched_barrier(0);
  asm volatile("s_waitcnt lgkmcnt(0)" ::: "memory");
  __builtin_amdgcn_s_barrier();
  __builtin_amdgcn_sched_barrier(0);
}

// ============================================================================
// Pre-pass: fp32 K/V -> bf16 images in the EXACT swizzled LDS chunk layout.
// (verbatim, verified)
// ============================================================================
__global__ __launch_bounds__(256)
void prep_kv(const float* __restrict__ K, const float* __restrict__ V,
             __bf16* __restrict__ KI, __bf16* __restrict__ VI)
{
  const int gid  = (int)blockIdx.x * 256 + (int)threadIdx.x; // 0..2M
  const int half = gid >> 20;              // 0=K, 1=V
  const int id   = gid & ((1 << 20) - 1);  // 0..1M
  const int chunk = id >> 9;               // 0..2047
  const int rem   = id & 511;
  const int bh = chunk >> 6, c = chunk & 63;
  const int b = bh >> 4, h = bh & 15;
  if (half == 0) {
    const int key = rem >> 4, dblk = rem & 15;
    const float* src = K + ((size_t)b * Sn + (size_t)c * 32 + key) * RS + h * Dn + dblk * 8;
    float4 a  = *(const float4*)src;
    float4 c2 = *(const float4*)(src + 4);
    bf16x8 f;
    f[0] = (__bf16)a.x;  f[1] = (__bf16)a.y;  f[2] = (__bf16)a.z;  f[3] = (__bf16)a.w;
    f[4] = (__bf16)c2.x; f[5] = (__bf16)c2.y; f[6] = (__bf16)c2.z; f[7] = (__bf16)c2.w;
    char* dst = (char*)KI + (size_t)chunk * 8192 + ((key * 256 + dblk * 16) ^ ((key & 7) << 4));
    *(bf16x8*)dst = f;
  } else {
    const int d = rem >> 2, koct = rem & 3;
    const float* src = V + ((size_t)b * Sn + (size_t)c * 32 + koct * 8) * RS + h * Dn + d;
    bf16x8 f;
#pragma unroll
    for (int j = 0; j < 8; ++j) f[j] = (__bf16)src[(size_t)j * RS];
    const int off = (d * 64 + koct * 16) ^ ((d & 3) << 4) ^ (((d >> 3) & 1) << 6);
    *(bf16x8*)((char*)VI + (size_t)chunk * 8192 + off) = f;
  }
}

// ============================================================================
// Main kernel R9: 512 blocks x 512 threads, 64 KB LDS -> 2 blocks/CU with
// FULLY OVERLAPPED lifetimes (R8 measured 1.84 us/unit at 16 waves vs ~3.0
// solo). Block = 64-query half-tile, 8 waves = 4 key-groups x 2 q-waves;
// superstep = 128 keys (group g computes chunk 4t+g). Sequential tile pair
// (15-p) then (p): EVERY block = 17 supersteps. Co-resident (bid,bid+256)
// = same head/pair, opposite query-half -> identical length, same K/V DMA
// stream (L2-friendly). Fixed slot-per-group rings (no ring arithmetic);
// double-barrier superstep: compute -> lgkm barrier -> DMA next chunks over
// just-read slots -> vmcnt barrier. Partner block's compute hides the DMA.
// 4-group merge tree = verified R7 pattern with wq in {0,1}.
// ============================================================================
__global__ __launch_bounds__(512)
void fa_fwd_dma4(const float* __restrict__ Q, const __bf16* __restrict__ KI,
                 const __bf16* __restrict__ VI, float* __restrict__ O)
{
  __shared__ __align__(16) __bf16 Klds[4][4096]; // 32 KB, slot = group
  __shared__ __align__(16) __bf16 Vt[4][4096];   // 32 KB, slot = group

  const int tid  = threadIdx.x;
  const int lane = tid & 63;
  const int wave = tid >> 6;    // 0..7
  const int col  = lane & 31;
  const int hi   = lane >> 5;
  const int grp  = wave >> 1;   // key-group 0..3: chunk 4t+grp
  const int wq   = wave & 1;    // q-wave: rows q0w..q0w+31

  const int xcd  = (int)blockIdx.x & 7;
  const int s    = (int)blockIdx.x >> 3;    // 0..63
  const int h2   = s & 3;
  const int pp   = (s >> 2) & 7;            // tile pair 0..7
  const int half = (s >> 5) & 1;            // query half of each tile
  const int hidx = xcd * 4 + h2;            // 0..31
  const int b    = hidx >> 4, h = hidx & 15;
  const size_t base = ((size_t)b * Sn) * RS + (size_t)h * Dn;

  const char* KIc = (const char*)KI + (size_t)hidx * 64 * 8192;
  const char* VIc = (const char*)VI + (size_t)hidx * 64 * 8192;

  // stage superstep ss: waves 0-3 -> K chunks 4ss+w into Kslot w;
  // waves 4-7 -> V chunks into Vslot w-4. 8x cp16 (1 KB rows) per wave.
  auto stageSS = [&](int ss) {
    const int c = 4 * ss + (wave & 3);
    const char* g = (wave < 4 ? KIc : VIc) + (size_t)c * 8192 + lane * 16;
    char* l = (char*)(wave < 4 ? &Klds[wave & 3][0] : &Vt[wave & 3][0]);
#pragma unroll
    for (int i = 0; i < 8; ++i) cp16(g + i * 1024, l + i * 1024);
  };

  const int cswz = (col & 7) << 4;
  const int vswz = ((col & 3) << 4) ^ (((col >> 3) & 1) << 6);

#pragma unroll 1
  for (int tp = 0; tp < 2; ++tp) {
    const int qt  = tp ? pp : (15 - pp);
    const int T   = qt + 1;                       // 128-key supersteps
    const int q0w = qt * QBLK + half * 64 + wq * 32;

    // ---- Q fragments, scaled ----
    bf16x8 qf[8];
    {
      const float* qp = Q + base + (size_t)(q0w + col) * RS + hi * 8;
#pragma unroll
      for (int kk = 0; kk < 8; ++kk) {
        float4 a = *(const float4*)(qp + kk * 16);
        float4 c2 = *(const float4*)(qp + kk * 16 + 4);
        bf16x8 f;
        f[0] = (__bf16)(a.x * QSCALE);  f[1] = (__bf16)(a.y * QSCALE);
        f[2] = (__bf16)(a.z * QSCALE);  f[3] = (__bf16)(a.w * QSCALE);
        f[4] = (__bf16)(c2.x * QSCALE); f[5] = (__bf16)(c2.y * QSCALE);
        f[6] = (__bf16)(c2.z * QSCALE); f[7] = (__bf16)(c2.w * QSCALE);
        qf[kk] = f;
      }
    }

    f32x16 o0 = {}, o1 = {}, o2 = {}, o3 = {};
    float m = -1e30f, l = 0.f;

    // ---- prologue: DMA superstep-0 chunks; wait ----
    stageSS(0);
    dma_barrier();

#pragma unroll 1
    for (int t = 0; t < T; ++t) {
      const int cc  = 4 * t + grp;
      const int kv0 = cc * 32;
      if (kv0 <= q0w + 31) {
        // ---- QK(t) ----
        f32x16 st = {};
        {
          const char* kb = (const char*)&Klds[grp][0];
          __builtin_amdgcn_s_setprio(1);
#pragma unroll
          for (int kk = 0; kk < 8; ++kk) {
            bf16x8 ka = *(const bf16x8*)(kb + ((col * 256 + kk * 32 + hi * 16) ^ cswz));
            st = mfma32(ka, qf[kk], st);
          }
          __builtin_amdgcn_s_setprio(0);
        }

        // ---- mask ----
        if (kv0 + KVBLK - 1 > q0w) {
          const int qk = q0w + col - kv0;
#pragma unroll
          for (int r = 0; r < 16; ++r) {
            const int krow = (r & 3) + 8 * (r >> 2) + 4 * hi;
            st[r] = (krow <= qk) ? st[r] : -1e30f;
          }
        }

        // ---- softmax ----
        float t8[8];
#pragma unroll
        for (int r = 0; r < 8; ++r) t8[r] = fmaxf(st[r], st[r + 8]);
#pragma unroll
        for (int r = 0; r < 4; ++r) t8[r] = fmaxf(t8[r], t8[r + 4]);
        const float pmax = pair_max(fmaxf(fmaxf(t8[0], t8[1]), fmaxf(t8[2], t8[3])), hi);

        if (!__all(pmax <= m + 11.0f)) {   // T13 defer-max
          const float mnew = fmaxf(m, pmax);
          const float al = __builtin_amdgcn_exp2f(m - mnew);
          m = mnew;
          l *= al;
#pragma unroll
          for (int r = 0; r < 16; ++r) {
            const int row = (r & 3) + 8 * (r >> 2) + 4 * hi;
            const float ar = lane_bcast(row, al);
            o0[r] *= ar; o1[r] *= ar; o2[r] *= ar; o3[r] *= ar;
          }
        }

        float s4[4] = {0.f, 0.f, 0.f, 0.f};
#pragma unroll
        for (int r = 0; r < 16; ++r) {
          st[r] = __builtin_amdgcn_exp2f(st[r] - m);
          s4[r & 3] += st[r];
        }
        l += pair_sum((s4[0] + s4[1]) + (s4[2] + s4[3]), hi);

        // ---- P -> A-fragments via 4 permlane32_swap ----
        unsigned cw[8];
#pragma unroll
        for (int i = 0; i < 8; ++i) cw[i] = pack2(st[2 * i], st[2 * i + 1]);
        union { unsigned u[4]; bf16x8 v; } pa0, pa1;
        {
          auto s02 = __builtin_amdgcn_permlane32_swap(cw[0], cw[2], false, false);
          auto s13 = __builtin_amdgcn_permlane32_swap(cw[1], cw[3], false, false);
          auto s46 = __builtin_amdgcn_permlane32_swap(cw[4], cw[6], false, false);
          auto s57 = __builtin_amdgcn_permlane32_swap(cw[5], cw[7], false, false);
          pa0.u[0] = s02[0]; pa0.u[2] = s02[1];
          pa0.u[1] = s13[0]; pa0.u[3] = s13[1];
          pa1.u[0] = s46[0]; pa1.u[2] = s46[1];
          pa1.u[1] = s57[0]; pa1.u[3] = s57[1];
        }

        // ---- PV(t) ----
        const char* vb = (const char*)&Vt[grp][0];
        __builtin_amdgcn_s_setprio(1);
#pragma unroll
        for (int ks = 0; ks < 2; ++ks) {
          const bf16x8 pa = ks ? pa1.v : pa0.v;
#define PV_STEP(ovar, dt) { \
          bf16x8 vf = *(const bf16x8*)(vb + ((((dt)*32 + col) * 64 + ks * 32 + hi * 16) ^ vswz)); \
          ovar = mfma32(pa, vf, ovar); }
          PV_STEP(o0, 0) PV_STEP(o1, 1) PV_STEP(o2, 2) PV_STEP(o3, 3)
#undef PV_STEP
        }
        __builtin_amdgcn_s_setprio(0);
      }

      pipeline_barrier();            // all reads of slots drained
      if (t + 1 < T) stageSS(t + 1); // overwrite slots with next chunks
      dma_barrier();                 // DMA landed; partner block hides this
    }

    // ---- merge 4 key-group partials: (1->0, 3->2), then (2->0) ----
    float* ob  = reinterpret_cast<float*>(&Klds[0][0]); // 8192 floats
    float* mlb = reinterpret_cast<float*>(&Vt[0][0]);
    float f0 = 1.f, f1 = 0.f;
    {
      const int src = grp & 1;                 // groups 1,3 are sources
      float* obr = ob  + (grp >> 1) * 4096;
      float* mlr = mlb + (grp >> 1) * 256;
      if (src) {
        mlr[wq * 128 + lane] = m;
        mlr[wq * 128 + 64 + lane] = l;
#pragma unroll
        for (int r = 0; r < 16; ++r) {
          obr[wq * 1024 + r * 64 + lane] = o0[r];
          obr[2048 + wq * 1024 + r * 64 + lane] = o1[r];
        }
      }
      __syncthreads();
      if (!src) {
        const float m1 = mlr[wq * 128 + lane];
        const float l1 = mlr[wq * 128 + 64 + lane];
        const float mS = fmaxf(m, m1);
        f0 = __builtin_amdgcn_exp2f(m - mS);
        f1 = __builtin_amdgcn_exp2f(m1 - mS);
        m = mS;
        l = l * f0 + l1 * f1;
#pragma unroll
        for (int r = 0; r < 16; ++r) {
          const int row = (r & 3) + 8 * (r >> 2) + 4 * hi;
          const float a0 = lane_bcast(row, f0), a1 = lane_bcast(row, f1);
          o0[r] = o0[r] * a0 + obr[wq * 1024 + r * 64 + lane] * a1;
          o1[r] = o1[r] * a0 + obr[2048 + wq * 1024 + r * 64 + lane] * a1;
        }
      }
      __syncthreads();
      if (src) {
#pragma unroll
        for (int r = 0; r < 16; ++r) {
          obr[wq * 1024 + r * 64 + lane] = o2[r];
          obr[2048 + wq * 1024 + r * 64 + lane] = o3[r];
        }
      }
      __syncthreads();
      if (!src) {
#pragma unroll
        for (int r = 0; r < 16; ++r) {
          const int row = (r & 3) + 8 * (r >> 2) + 4 * hi;
          const float a0 = lane_bcast(row, f0), a1 = lane_bcast(row, f1);
          o2[r] = o2[r] * a0 + obr[wq * 1024 + r * 64 + lane] * a1;
          o3[r] = o3[r] * a0 + obr[2048 + wq * 1024 + r * 64 + lane] * a1;
        }
      }
      __syncthreads();
    }
    {
      if (grp == 2) {
        mlb[wq * 128 + lane] = m;
        mlb[wq * 128 + 64 + lane] = l;
#pragma unroll
        for (int r = 0; r < 16; ++r) {
          ob[wq * 1024 + r * 64 + lane] = o0[r];
          ob[2048 + wq * 1024 + r * 64 + lane] = o1[r];
        }
      }
      __syncthreads();
      if (grp == 0) {
        const float m1 = mlb[wq * 128 + lane];
        const float l1 = mlb[wq * 128 + 64 + lane];
        const float mS = fmaxf(m, m1);
        f0 = __builtin_amdgcn_exp2f(m - mS);
        f1 = __builtin_amdgcn_exp2f(m1 - mS);
        l = l * f0 + l1 * f1;
#pragma unroll
        for (int r = 0; r < 16; ++r) {
          const int row = (r & 3) + 8 * (r >> 2) + 4 * hi;
          const float a0 = lane_bcast(row, f0), a1 = lane_bcast(row, f1);
          o0[r] = o0[r] * a0 + ob[wq * 1024 + r * 64 + lane] * a1;
          o1[r] = o1[r] * a0 + ob[2048 + wq * 1024 + r * 64 + lane] * a1;
        }
      }
      __syncthreads();
      if (grp == 2) {
#pragma unroll
        for (int r = 0; r < 16; ++r) {
          ob[wq * 1024 + r * 64 + lane] = o2[r];
          ob[2048 + wq * 1024 + r * 64 + lane] = o3[r];
        }
      }
      __syncthreads();
      if (grp == 0) {
#pragma unroll
        for (int r = 0; r < 16; ++r) {
          const int row = (r & 3) + 8 * (r >> 2) + 4 * hi;
          const float a0 = lane_bcast(row, f0), a1 = lane_bcast(row, f1);
          o2[r] = o2[r] * a0 + ob[wq * 1024 + r * 64 + lane] * a1;
          o3[r] = o3[r] * a0 + ob[2048 + wq * 1024 + r * 64 + lane] * a1;
        }
        // ---- epilogue: store this half-tile ----
        const float linv = 1.0f / l;
#pragma unroll
        for (int r = 0; r < 16; ++r) {
          const int row = (r & 3) + 8 * (r >> 2) + 4 * hi;
          const float lr = lane_bcast(row, linv);
          float* op = O + base + (size_t)(q0w + row) * RS + col;
          op[0]  = o0[r] * lr;
          op[32] = o1[r] * lr;
          op[64] = o2[r] * lr;
          op[96] = o3[r] * lr;
        }
      }
    }
    __syncthreads();   // protect merge scratch before next tile's staging
  }
}

// ============================================================================
// Fallback: verbatim R5 kernel (104 µs) if workspace is too small.
// ============================================================================
__global__ __launch_bounds__(512)
void fa_fwd_reg(const float* __restrict__ Q, const float* __restrict__ K,
                const float* __restrict__ V, float* __restrict__ O)
{
  __shared__ __align__(16) __bf16 Klds[6][KVBLK * 128];
  __shared__ __align__(16) __bf16 Vt[4][128 * KVBLK];

  const int tid  = threadIdx.x;
  const int lane = tid & 63;
  const int wave = tid >> 6;
  const int col  = lane & 31;
  const int hi   = lane >> 5;
  const int grp  = wave >> 2;
  const int wq   = wave & 3;

  const int xcd  = (int)blockIdx.x & 7;
  const int s    = (int)blockIdx.x >> 3;
  const int hidx = xcd * 4 + (s & 3);
  const int b    = hidx >> 4, h = hidx & 15;
  const int s2   = s >> 2;
  const int qt   = (s < 32) ? (15 - s2) : (s2 - 8);
  const int q0w  = qt * QBLK + wq * 32;
  const int T    = 2 * (qt + 1);
  const size_t base = ((size_t)b * Sn) * RS + (size_t)h * Dn;

  const int sthalf = tid >> 8, ht = tid & 255;
  const int skey = ht >> 3, sd = (ht & 7) * 16;
  const int vkey4 = (ht & 7) * 4, vd4 = (ht >> 3) * 4;

  float4 kr[4], vr[4];
  auto loadK = [&](int ss) {
    const int kv0 = (2 * ss + sthalf) * KVBLK;
    const float* kp = K + base + (size_t)(kv0 + skey) * RS + sd;
#pragma unroll
    for (int i = 0; i < 4; ++i) kr[i] = *(const float4*)(kp + 4 * i);
  };
  auto loadV = [&](int ss) {
    const int kv0 = (2 * ss + sthalf) * KVBLK;
    const float* vp = V + base + (size_t)(kv0 + vkey4) * RS + vd4;
#pragma unroll
    for (int i = 0; i < 4; ++i) vr[i] = *(const float4*)(vp + (size_t)i * RS);
  };
  auto stageK = [&](int ss) {
    char* kb = (char*)&Klds[(2 * ss + sthalf) % 6][0];
    const int kbase = skey * 256 + sd * 2;
    const int kswz  = (skey & 7) << 4;
#pragma unroll
    for (int i = 0; i < 2; ++i) {
      bf16x8 f;
      f[0] = (__bf16)kr[2*i].x;   f[1] = (__bf16)kr[2*i].y;
      f[2] = (__bf16)kr[2*i].z;   f[3] = (__bf16)kr[2*i].w;
      f[4] = (__bf16)kr[2*i+1].x; f[5] = (__bf16)kr[2*i+1].y;
      f[6] = (__bf16)kr[2*i+1].z; f[7] = (__bf16)kr[2*i+1].w;
      *(bf16x8*)(kb + ((kbase + 16 * i) ^ kswz)) = f;
    }
  };
  auto stageV = [&](int ss) {
    char* vb = (char*)&Vt[(2 * ss + sthalf) & 3][0];
    const int b6 = ((vd4 >> 3) & 1) << 6;
#pragma unroll
    for (int j = 0; j < 4; ++j) {
      bf16x4 w;
      w[0] = (__bf16)f4e(vr[0], j);
      w[1] = (__bf16)f4e(vr[1], j);
      w[2] = (__bf16)f4e(vr[2], j);
      w[3] = (__bf16)f4e(vr[3], j);
      const int addr = (((vd4 + j) * 64 + vkey4 * 2) ^ (j << 4)) ^ b6;
      *(bf16x4*)(vb + addr) = w;
    }
  };

  const int cswz = (col & 7) << 4;
  const int vswz = ((col & 3) << 4) ^ (((col >> 3) & 1) << 6);

  bf16x8 qf[8];
  {
    const float* qp = Q + base + (size_t)(q0w + col) * RS + hi * 8;
#pragma unroll
    for (int kk = 0; kk < 8; ++kk) {
      float4 a = *(const float4*)(qp + kk * 16);
      float4 c2 = *(const float4*)(qp + kk * 16 + 4);
      bf16x8 f;
      f[0] = (__bf16)(a.x * QSCALE);  f[1] = (__bf16)(a.y * QSCALE);
      f[2] = (__bf16)(a.z * QSCALE);  f[3] = (__bf16)(a.w * QSCALE);
      f[4] = (__bf16)(c2.x * QSCALE); f[5] = (__bf16)(c2.y * QSCALE);
      f[6] = (__bf16)(c2.z * QSCALE); f[7] = (__bf16)(c2.w * QSCALE);
      qf[kk] = f;
    }
  }

  f32x16 o0 = {}, o1 = {}, o2 = {}, o3 = {};
  float m = -1e30f, l = 0.f;

  loadK(0); loadV(0);
  stageK(0);
  loadK(1);
  stageV(0);
  loadV(1);
  stageK(1);
  if (2 < T) loadK(2);
  pipeline_barrier();

  f32x16 st_cur = {};
  if (grp * KVBLK <= q0w + 31) {
    const char* kb = (const char*)&Klds[grp][0];
    __builtin_amdgcn_s_setprio(1);
#pragma unroll
    for (int kk = 0; kk < 8; ++kk) {
      bf16x8 ka = *(const bf16x8*)(kb + ((col * 256 + kk * 32 + hi * 16) ^ cswz));
      st_cur = mfma32(ka, qf[kk], st_cur);
    }
    __builtin_amdgcn_s_setprio(0);
  }

#pragma unroll 1
  for (int t = 0; t < T; ++t) {
    f32x16 stn = {};
    const int icn = 2 * (t + 1) + grp;
    if (t + 1 < T && icn * KVBLK <= q0w + 31) {
      const char* kb = (const char*)&Klds[icn % 6][0];
      __builtin_amdgcn_s_setprio(1);
#pragma unroll
      for (int kk = 0; kk < 8; ++kk) {
        bf16x8 ka = *(const bf16x8*)(kb + ((col * 256 + kk * 32 + hi * 16) ^ cswz));
        stn = mfma32(ka, qf[kk], stn);
      }
      __builtin_amdgcn_s_setprio(0);
    }

    if (t + 2 < T) stageK(t + 2);
    if (t + 1 < T) stageV(t + 1);
    if (t + 3 < T) loadK(t + 3);
    if (t + 2 < T) loadV(t + 2);

    const int kv0 = (2 * t + grp) * KVBLK;
    if (kv0 <= q0w + 31) {
      if (kv0 + KVBLK - 1 > q0w) {
        const int qk = q0w + col - kv0;
#pragma unroll
        for (int r = 0; r < 16; ++r) {
          const int krow = (r & 3) + 8 * (r >> 2) + 4 * hi;
          st_cur[r] = (krow <= qk) ? st_cur[r] : -1e30f;
        }
      }

      float t8[8];
#pragma unroll
      for (int r = 0; r < 8; ++r) t8[r] = fmaxf(st_cur[r], st_cur[r + 8]);
#pragma unroll
      for (int r = 0; r < 4; ++r) t8[r] = fmaxf(t8[r], t8[r + 4]);
      const float pmax = pair_max(fmaxf(fmaxf(t8[0], t8[1]), fmaxf(t8[2], t8[3])), hi);

      if (!__all(pmax <= m + 11.0f)) {
        const float mnew = fmaxf(m, pmax);
        const float al = __builtin_amdgcn_exp2f(m - mnew);
        m = mnew;
        l *= al;
#pragma unroll
        for (int r = 0; r < 16; ++r) {
          const int row = (r & 3) + 8 * (r >> 2) + 4 * hi;
          const float ar = lane_bcast(row, al);
          o0[r] *= ar; o1[r] *= ar; o2[r] *= ar; o3[r] *= ar;
        }
      }

      float s4[4] = {0.f, 0.f, 0.f, 0.f};
#pragma unroll
      for (int r = 0; r < 16; ++r) {
        st_cur[r] = __builtin_amdgcn_exp2f(st_cur[r] - m);
        s4[r & 3] += st_cur[r];
      }
      l += pair_sum((s4[0] + s4[1]) + (s4[2] + s4[3]), hi);

      unsigned cw[8];
#pragma unroll
      for (int i = 0; i < 8; ++i) cw[i] = pack2(st_cur[2 * i], st_cur[2 * i + 1]);
      union { unsigned u[4]; bf16x8 v; } pa0, pa1;
      {
        auto s02 = __builtin_amdgcn_permlane32_swap(cw[0], cw[2], false, false);
        auto s13 = __builtin_amdgcn_permlane32_swap(cw[1], cw[3], false, false);
        auto s46 = __builtin_amdgcn_permlane32_swap(cw[4], cw[6], false, false);
        auto s57 = __builtin_amdgcn_permlane32_swap(cw[5], cw[7], false, false);
        pa0.u[0] = s02[0]; pa0.u[2] = s02[1];
        pa0.u[1] = s13[0]; pa0.u[3] = s13[1];
        pa1.u[0] = s46[0]; pa1.u[2] = s46[1];
        pa1.u[1] = s57[0]; pa1.u[3] = s57[1];
      }

      const char* vb = (const char*)&Vt[(2 * t + grp) & 3][0];
      __builtin_amdgcn_s_setprio(1);
#pragma unroll
      for (int ks = 0; ks < 2; ++ks) {
        const bf16x8 pa = ks ? pa1.v : pa0.v;
#define PV_STEP(ovar, dt) { \
        bf16x8 vf = *(const bf16x8*)(vb + ((((dt)*32 + col) * 64 + ks * 32 + hi * 16) ^ vswz)); \
        ovar = mfma32(pa, vf, ovar); }
        PV_STEP(o0, 0) PV_STEP(o1, 1) PV_STEP(o2, 2) PV_STEP(o3, 3)
#undef PV_STEP
      }
      __builtin_amdgcn_s_setprio(0);
    }
    pipeline_barrier();
    st_cur = stn;
  }

  float* ob  = reinterpret_cast<float*>(&Klds[0][0]);
  float* mlb = reinterpret_cast<float*>(&Vt[0][0]);
  if (grp == 1) {
    mlb[wq * 128 + lane] = m;
    mlb[wq * 128 + 64 + lane] = l;
#pragma unroll
    for (int r = 0; r < 16; ++r) {
      ob[wq * 1024 + r * 64 + lane] = o0[r];
      ob[4096 + wq * 1024 + r * 64 + lane] = o1[r];
    }
  }
  __syncthreads();
  float f0 = 1.f, f1 = 0.f;
  if (grp == 0) {
    const float m1 = mlb[wq * 128 + lane];
    const float l1 = mlb[wq * 128 + 64 + lane];
    const float mS = fmaxf(m, m1);
    f0 = __builtin_amdgcn_exp2f(m - mS);
    f1 = __builtin_amdgcn_exp2f(m1 - mS);
    l = l * f0 + l1 * f1;
#pragma unroll
    for (int r = 0; r < 16; ++r) {
      const int row = (r & 3) + 8 * (r >> 2) + 4 * hi;
      const float a0 = lane_bcast(row, f0), a1 = lane_bcast(row, f1);
      o0[r] = o0[r] * a0 + ob[wq * 1024 + r * 64 + lane] * a1;
      o1[r] = o1[r] * a0 + ob[4096 + wq * 1024 + r * 64 + lane] * a1;
    }
  }
  __syncthreads();
  if (grp == 1) {
#pragma unroll
    for (int r = 0; r < 16; ++r) {
      ob[wq * 1024 + r * 64 + lane] = o2[r];
      ob[4096 + wq * 1024 + r * 64 + lane] = o3[r];
    }
  }
  __syncthreads();
  if (grp == 0) {
#pragma unroll
    for (int r = 0; r < 16; ++r) {
      const int row = (r & 3) + 8 * (r >> 2) + 4 * hi;
      const float a0 = lane_bcast(row, f0), a1 = lane_bcast(row, f1);
      o2[r] = o2[r] * a0 + ob[wq * 1024 + r * 64 + lane] * a1;
      o3[r] = o3[r] * a0 + ob[4096 + wq * 1024 + r * 64 + lane] * a1;
    }
    const float linv = 1.0f / l;
#pragma unroll
    for (int r = 0; r < 16; ++r) {
      const int row = (r & 3) + 8 * (r >> 2) + 4 * hi;
      const float lr = lane_bcast(row, linv);
      float* op = O + base + (size_t)(q0w + row) * RS + col;
      op[0]  = o0[r] * lr;
      op[32] = o1[r] * lr;
      op[64] = o2[r] * lr;
      op[96] = o3[r] * lr;
    }
  }
}

} // namespace

extern "C" void kernel_launch(void* const* d_in, const int* /*in_sizes*/, int /*n_in*/,
                              void* d_out, int /*out_size*/, void* d_ws, size_t ws_size,
                              hipStream_t stream) {
  const float* q = (const float*)d_in[0];
  const float* k = (const float*)d_in[1];
  const float* v = (const float*)d_in[2];
  float* o = (float*)d_out;
  if (d_ws != nullptr && ws_size >= WS_NEED) {
    __bf16* ki = (__bf16*)d_ws;
    __bf16* vi = (__bf16*)((char*)d_ws + IMG_BYTES);
    hipLaunchKernelGGL(prep_kv, dim3(8192), dim3(256), 0, stream, k, v, ki, vi);
    hipLaunchKernelGGL(fa_fwd_dma4, dim3(512), dim3(512), 0, stream, q, ki, vi, o);
  } else {
    hipLaunchKernelGGL(fa_fwd_reg, dim3(512), dim3(512), 0, stream, q, k, v, o);
  }
}